// Round 13
// baseline (198.581 us; speedup 1.0000x reference)
//
#include <hip/hip_runtime.h>
#include <hip/hip_bf16.h>

using bf16 = __hip_bfloat16;
typedef __attribute__((ext_vector_type(8))) short short8;
typedef __attribute__((ext_vector_type(4))) float f32x4;

#define AS1U(p) ((const __attribute__((address_space(1))) unsigned int*)(p))
#define AS3U(p) ((__attribute__((address_space(3))) unsigned int*)(p))

__device__ __forceinline__ float bflo(unsigned u) { return __uint_as_float(u << 16); }
__device__ __forceinline__ float bfhi(unsigned u) { return __uint_as_float(u & 0xffff0000u); }
__device__ __forceinline__ unsigned short f2bf(float f) {
    union { float f; unsigned u; } v{f};
    unsigned r = v.u + 0x7fffu + ((v.u >> 16) & 1u);   // RNE (finite values only)
    return (unsigned short)(r >> 16);
}

// ---- prep: weight transposes (f32->bf16) + pos_avg[n][c] = 0.5*(pos[8n+3]+pos[8n+4]) bf16 ----
__global__ __launch_bounds__(256) void kprep(const float* __restrict__ wq,
                                             const float* __restrict__ wp,
                                             const float* __restrict__ pos,
                                             bf16* __restrict__ wqT,
                                             bf16* __restrict__ wpT,
                                             bf16* __restrict__ posavg) {
    int bid = blockIdx.x;
    __shared__ float t[32][33];
    if (bid < 1024) {
        const float* in; bf16* out; int Cc, bx, by;
        if (bid < 768) { in = wq; out = wqT; Cc = 1536; bx = bid % 48; by = bid / 48; }
        else { int i = bid - 768; in = wp; out = wpT; Cc = 512; bx = i & 15; by = i >> 4; }
        const int R = 512;
        int tx = threadIdx.x & 31, ty = threadIdx.x >> 5;
        int c0 = bx * 32, r0 = by * 32;
#pragma unroll
        for (int i = 0; i < 4; ++i)
            t[ty + i * 8][tx] = in[(size_t)(r0 + ty + i * 8) * Cc + c0 + tx];
        __syncthreads();
#pragma unroll
        for (int i = 0; i < 4; ++i)
            out[(size_t)(c0 + ty + i * 8) * R + r0 + tx] = __float2bfloat16(t[tx][ty + i * 8]);
    } else {
        size_t idx = (size_t)(bid - 1024) * 256 + threadIdx.x;   // 262,144 threads x 8 elems
        size_t e = idx * 8;
        int n = (int)(e >> 9);
        int c = (int)(e & 511);
        const float* p3 = pos + (size_t)(n * 8 + 3) * 512 + c;
        const float* p4 = pos + (size_t)(n * 8 + 4) * 512 + c;
        unsigned r[4];
#pragma unroll
        for (int h = 0; h < 2; ++h) {
            float4 a = *(const float4*)(p3 + h * 4);
            float4 b = *(const float4*)(p4 + h * 4);
            float v0 = 0.5f * (a.x + b.x), v1 = 0.5f * (a.y + b.y);
            float v2 = 0.5f * (a.z + b.z), v3 = 0.5f * (a.w + b.w);
            r[h * 2]     = (unsigned)f2bf(v0) | ((unsigned)f2bf(v1) << 16);
            r[h * 2 + 1] = (unsigned)f2bf(v2) | ((unsigned)f2bf(v3) << 16);
        }
        *(uint4*)(posavg + e) = *(uint4*)r;
    }
}

// Shared LDS byte formula (verified R5-R11, 0 conflicts):
// byte(R,g) = (R>>4)*1024 + ((R>>1)&7)*128 + ((g | ((R&1)<<2)) ^ ((R>>1)&7))*16

// ======== FUSED qkv GEMM: C = (x + posavg) @ Bt^T + bias ========
// R7 ring-4 structure; A reg-staged with PARITY-DOUBLE-BUFFERED regs (tile k -> buf k&1).
// Region t order: ldA(t+3)->buf[(t+3)&1]; stageB(t+3); cvtWriteA(t+2) from buf[(t+2)&1]
// (different parity -> no overwrite; implicit wait = vmcnt(10), which also proves B(t+1)
// landed). 12 ds_read; 32 MFMA; lgkm(0); vmcnt belt; s_barrier. Fixes R12's wrong-tile bug.
__global__ __launch_bounds__(512, 2) void kgemmF(const float* __restrict__ X,
                                                 const bf16* __restrict__ posavg,
                                                 const bf16* __restrict__ Bt,
                                                 const float* __restrict__ bias,
                                                 bf16* __restrict__ C) {
    constexpr int K = 512, N = 1536;
    __shared__ __align__(16) char smem[131072];  // 4 slots x (A 16K + B 16K)
    const int tid = threadIdx.x;
    const int lane = tid & 63, wave = tid >> 6;
    const int wm = wave >> 2, wn = wave & 3;
    const int fr = lane & 15;
    const int g = lane >> 4;

    const int p_rd = (((fr & 1) << 2) | g) ^ ((fr >> 1) & 7);
    const int tbA = (wm * 64 + (fr >> 1)) * 128 + p_rd * 16;
    const int tbB = (wn * 32 + (fr >> 1)) * 128 + p_rd * 16;

    const int ntn = N >> 8;
    const int nwg = gridDim.x;
    const int bid = blockIdx.x;
    const int swz = (bid & 7) * (nwg >> 3) + (bid >> 3);
    const int bm = (swz / ntn) << 8;
    const int bn = (swz % ntn) << 8;

    // B staging (gload_lds, linear dest, pre-permuted source) — R7-proven
    const int q = (lane & 7) ^ (lane >> 3);
    const int srow = wave * 32 + 2 * (lane >> 3) + ((q >> 2) & 1);
    const int scol = (q & 3) * 8;
    const bf16* sB0 = Bt + (size_t)(bn + srow) * K + scol;
    const bf16* sB1 = Bt + (size_t)(bn + srow + 16) * K + scol;
    const int dA0 = wave * 2048, dA1 = wave * 2048 + 1024;
    auto stageB = [&](int kt, int slot) {
        char* d = smem + slot * 32768 + 16384;
        __builtin_amdgcn_global_load_lds(AS1U(sB0 + kt * 32), AS3U(d + dA0), 16, 0, 0);
        __builtin_amdgcn_global_load_lds(AS1U(sB1 + kt * 32), AS3U(d + dA1), 16, 0, 0);
    };

    // A staging (reg: x f32 + posavg bf16 -> bf16, ds_write swizzled); parity-dbuf regs
    const int rA = wave * 32 + (lane >> 1);          // local row 0..255
    const int gA0 = (lane & 1) * 2;                  // chunks gA0, gA0+1
    const int mrow = bm + rA;
    const float* xrow = X + (size_t)mrow * K;
    const bf16* prow = posavg + (size_t)(mrow & 4095) * K;
    const int abase = (rA >> 4) * 1024 + ((rA >> 1) & 7) * 128;
    const int asw = (rA >> 1) & 7, ahi = (rA & 1) << 2;
    const int ad0 = abase + (((gA0)     | ahi) ^ asw) * 16;
    const int ad1 = abase + (((gA0 + 1) | ahi) ^ asw) * 16;

    f32x4 ax[2][4]; uint4 ap[2][2];                  // [parity][...]; indices compile-time
    auto ldA = [&](int kt, int p) {
        const float* xs = xrow + kt * 32 + gA0 * 8;
#pragma unroll
        for (int i = 0; i < 4; ++i) ax[p][i] = *(const f32x4*)(xs + i * 4);
        const bf16* ps = prow + kt * 32 + gA0 * 8;
        ap[p][0] = *(const uint4*)(ps);
        ap[p][1] = *(const uint4*)(ps + 8);
    };
    auto cvtWriteA = [&](int slot, int p) {
        char* d = smem + slot * 32768;
#pragma unroll
        for (int j = 0; j < 2; ++j) {
            const float* xf = (const float*)&ax[p][2 * j];
            const unsigned* pu = &ap[p][j].x;
            unsigned out[4];
#pragma unroll
            for (int w = 0; w < 4; ++w) {
                float lo = xf[2 * w]     + bflo(pu[w]);
                float hi = xf[2 * w + 1] + bfhi(pu[w]);
                out[w] = (unsigned)f2bf(lo) | ((unsigned)f2bf(hi) << 16);
            }
            *(uint4*)(d + (j ? ad1 : ad0)) = *(uint4*)out;
        }
    };

    f32x4 acc[8][4];
#pragma unroll
    for (int i = 0; i < 8; ++i)
#pragma unroll
        for (int j = 0; j < 4; ++j) acc[i][j] = f32x4{0.f, 0.f, 0.f, 0.f};

    // ---- prologue: tile k -> reg-buf k&1; consume before that buf is reloaded
    ldA(0, 0); stageB(0, 0);
    ldA(1, 1); stageB(1, 1);
    cvtWriteA(0, 0);          // tile 0 from buf0
    ldA(2, 0); stageB(2, 2);  // tile 2 -> buf0 (tile 0 already consumed)
    cvtWriteA(1, 1);          // tile 1 from buf1
    asm volatile("s_waitcnt lgkmcnt(0)" ::: "memory");
    __builtin_amdgcn_sched_barrier(0);
    __builtin_amdgcn_s_barrier();

#pragma unroll
    for (int t = 0; t < 16; ++t) {
        const int rd = t & 3;
        const char* pa = smem + rd * 32768;
        const char* pb = pa + 16384;
        if (t < 13) { ldA(t + 3, (t + 3) & 1); stageB(t + 3, (t + 3) & 3); }
        if (t <= 13) cvtWriteA((t + 2) & 3, (t + 2) & 1);  // consume buf (t+2)&1: vmcnt(10)
        short8 af[8], bfr[4];
#pragma unroll
        for (int mi = 0; mi < 8; ++mi) af[mi] = *(const short8*)(pa + tbA + mi * 1024);
#pragma unroll
        for (int nj = 0; nj < 4; ++nj) bfr[nj] = *(const short8*)(pb + tbB + nj * 1024);
#pragma unroll
        for (int mi = 0; mi < 8; ++mi)
#pragma unroll
            for (int nj = 0; nj < 4; ++nj)
                acc[mi][nj] = __builtin_amdgcn_mfma_f32_16x16x32_bf16(af[mi], bfr[nj], acc[mi][nj], 0, 0, 0);
        asm volatile("s_waitcnt lgkmcnt(0)" ::: "memory");
        if (t <= 12)      asm volatile("s_waitcnt vmcnt(16)" ::: "memory");  // belt (no-op steady)
        else if (t == 13) asm volatile("s_waitcnt vmcnt(4)" ::: "memory");
        else if (t == 14) asm volatile("s_waitcnt vmcnt(0)" ::: "memory");
        __builtin_amdgcn_sched_barrier(0);
        __builtin_amdgcn_s_barrier();
    }

#pragma unroll
    for (int mi = 0; mi < 8; ++mi) {
#pragma unroll
        for (int nj = 0; nj < 4; ++nj) {
            int col = bn + wn * 64 + nj * 16 + fr;
            int row0 = bm + wm * 128 + mi * 16 + (lane >> 4) * 4;
            float bv = bias[col];
#pragma unroll
            for (int rr = 0; rr < 4; ++rr)
                C[(size_t)(row0 + rr) * N + col] = (bf16)__float2bfloat16(acc[mi][nj][rr] + bv);
        }
    }
}

// ======== 256x256 GEMM ring-4 (R7, proven) — proj ========
template <typename OutT>
__global__ __launch_bounds__(512, 2) void kgemm8(const bf16* __restrict__ A,
                                                 const bf16* __restrict__ Bt,
                                                 const float* __restrict__ bias,
                                                 OutT* __restrict__ C,
                                                 int M, int N, int K_) {
    constexpr int K = 512;
    __shared__ __align__(16) char smem[131072];
    const int tid = threadIdx.x;
    const int lane = tid & 63, wave = tid >> 6;
    const int wm = wave >> 2, wn = wave & 3;
    const int fr = lane & 15;
    const int g = lane >> 4;

    const int p_rd = (((fr & 1) << 2) | g) ^ ((fr >> 1) & 7);
    const int tbA = (wm * 64 + (fr >> 1)) * 128 + p_rd * 16;
    const int tbB = (wn * 32 + (fr >> 1)) * 128 + p_rd * 16;

    const int ntn = N >> 8;
    const int nwg = gridDim.x;
    const int bid = blockIdx.x;
    const int swz = (bid & 7) * (nwg >> 3) + (bid >> 3);
    const int bm = (swz / ntn) << 8;
    const int bn = (swz % ntn) << 8;

    const int q = (lane & 7) ^ (lane >> 3);
    const int srow = wave * 32 + 2 * (lane >> 3) + ((q >> 2) & 1);
    const int scol = (q & 3) * 8;
    const bf16* sA[2]; const bf16* sB[2];
#pragma unroll
    for (int g2 = 0; g2 < 2; ++g2) {
        sA[g2] = A  + (size_t)(bm + srow + g2 * 16) * K + scol;
        sB[g2] = Bt + (size_t)(bn + srow + g2 * 16) * K + scol;
    }
    const int dA0 = wave * 2048, dA1 = wave * 2048 + 1024;

    f32x4 acc[8][4];
#pragma unroll
    for (int i = 0; i < 8; ++i)
#pragma unroll
        for (int j = 0; j < 4; ++j) acc[i][j] = f32x4{0.f, 0.f, 0.f, 0.f};

    auto stageA = [&](int kt, int slot) {
        char* d = smem + slot * 32768;
        __builtin_amdgcn_global_load_lds(AS1U(sA[0] + kt * 32), AS3U(d + dA0), 16, 0, 0);
        __builtin_amdgcn_global_load_lds(AS1U(sA[1] + kt * 32), AS3U(d + dA1), 16, 0, 0);
    };
    auto stageB = [&](int kt, int slot) {
        char* d = smem + slot * 32768 + 16384;
        __builtin_amdgcn_global_load_lds(AS1U(sB[0] + kt * 32), AS3U(d + dA0), 16, 0, 0);
        __builtin_amdgcn_global_load_lds(AS1U(sB[1] + kt * 32), AS3U(d + dA1), 16, 0, 0);
    };

    stageA(0, 0); stageB(0, 0);
    stageA(1, 1); stageB(1, 1);
    stageA(2, 2); stageB(2, 2);
    asm volatile("s_waitcnt vmcnt(8)" ::: "memory");
    __builtin_amdgcn_s_barrier();

#pragma unroll
    for (int t = 0; t < 16; ++t) {
        const int rd = t & 3, wrs = (t + 3) & 3;
        const char* pa = smem + rd * 32768;
        const char* pb = pa + 16384;
        if (t < 13) { stageA(t + 3, wrs); stageB(t + 3, wrs); }
        short8 af[8], bfr[4];
#pragma unroll
        for (int mi = 0; mi < 8; ++mi) af[mi] = *(const short8*)(pa + tbA + mi * 1024);
#pragma unroll
        for (int nj = 0; nj < 4; ++nj) bfr[nj] = *(const short8*)(pb + tbB + nj * 1024);
#pragma unroll
        for (int mi = 0; mi < 8; ++mi)
#pragma unroll
            for (int nj = 0; nj < 4; ++nj)
                acc[mi][nj] = __builtin_amdgcn_mfma_f32_16x16x32_bf16(af[mi], bfr[nj], acc[mi][nj], 0, 0, 0);
        asm volatile("s_waitcnt lgkmcnt(0)" ::: "memory");
        if (t <= 12)      asm volatile("s_waitcnt vmcnt(8)" ::: "memory");
        else if (t == 13) asm volatile("s_waitcnt vmcnt(4)" ::: "memory");
        else if (t == 14) asm volatile("s_waitcnt vmcnt(0)" ::: "memory");
        __builtin_amdgcn_sched_barrier(0);
        __builtin_amdgcn_s_barrier();
    }

#pragma unroll
    for (int mi = 0; mi < 8; ++mi) {
#pragma unroll
        for (int nj = 0; nj < 4; ++nj) {
            int col = bn + wn * 64 + nj * 16 + fr;
            int row0 = bm + wm * 128 + mi * 16 + (lane >> 4) * 4;
            float bv = bias[col];
#pragma unroll
            for (int rr = 0; rr < 4; ++rr) {
                float val = acc[mi][nj][rr] + bv;
                if constexpr (sizeof(OutT) == 2)
                    C[(size_t)(row0 + rr) * N + col] = (OutT)__float2bfloat16(val);
                else
                    C[(size_t)(row0 + rr) * N + col] = (OutT)val;
            }
        }
    }
}

// ---------------- 8x8 per-token head attention + scrambled write ----------------
__global__ __launch_bounds__(256) void kattn(const bf16* __restrict__ qkv,
                                             bf16* __restrict__ oscr) {
    int T = blockIdx.x * 256 + threadIdx.x;
    int token = T >> 3, head = T & 7;
    int b = token >> 12, n = token & 4095;
    const bf16* row = qkv + (size_t)token * 1536;

    uint4 qp[8];
#pragma unroll
    for (int c = 0; c < 8; ++c) qp[c] = *(const uint4*)(row + head * 64 + c * 8);

    float s[8];
#pragma unroll
    for (int j = 0; j < 8; ++j) {
        float acc = 0.f;
#pragma unroll
        for (int c = 0; c < 8; ++c) {
            uint4 kp = *(const uint4*)(row + 512 + j * 64 + c * 8);
            const unsigned* ku = &kp.x; const unsigned* qu = &qp[c].x;
#pragma unroll
            for (int w = 0; w < 4; ++w) {
                acc = fmaf(bflo(qu[w]), bflo(ku[w]), acc);
                acc = fmaf(bfhi(qu[w]), bfhi(ku[w]), acc);
            }
        }
        s[j] = acc * 0.125f;
    }
    float mx = s[0];
#pragma unroll
    for (int j = 1; j < 8; ++j) mx = fmaxf(mx, s[j]);
    float sum = 0.f;
#pragma unroll
    for (int j = 0; j < 8; ++j) { s[j] = __expf(s[j] - mx); sum += s[j]; }
    float inv = 1.f / sum;
#pragma unroll
    for (int j = 0; j < 8; ++j) s[j] *= inv;

    float o[64];
#pragma unroll
    for (int d = 0; d < 64; ++d) o[d] = 0.f;
#pragma unroll
    for (int j = 0; j < 8; ++j) {
        float pj = s[j];
#pragma unroll
        for (int c = 0; c < 8; ++c) {
            uint4 vp = *(const uint4*)(row + 1024 + j * 64 + c * 8);
            const unsigned* vu = &vp.x;
#pragma unroll
            for (int w = 0; w < 4; ++w) {
                o[c * 8 + w * 2]     = fmaf(pj, bflo(vu[w]), o[c * 8 + w * 2]);
                o[c * 8 + w * 2 + 1] = fmaf(pj, bfhi(vu[w]), o[c * 8 + w * 2 + 1]);
            }
        }
    }
    size_t orow = (size_t)b * 4096 + head * 512 + (n >> 3);
    bf16* op = oscr + orow * 512 + (n & 7) * 64;
#pragma unroll
    for (int c = 0; c < 8; ++c) {
        unsigned rr[4];
#pragma unroll
        for (int w = 0; w < 4; ++w)
            rr[w] = (unsigned)f2bf(o[c * 8 + w * 2]) | ((unsigned)f2bf(o[c * 8 + w * 2 + 1]) << 16);
        *(uint4*)(op + c * 8) = *(uint4*)rr;
    }
}

extern "C" void kernel_launch(void* const* d_in, const int* in_sizes, int n_in,
                              void* d_out, int out_size, void* d_ws, size_t ws_size,
                              hipStream_t stream) {
    const float* x      = (const float*)d_in[0];
    const float* pos32  = (const float*)d_in[1];
    const float* w_qkv  = (const float*)d_in[2];
    const float* b_qkv  = (const float*)d_in[3];
    const float* w_proj = (const float*)d_in[4];
    const float* b_proj = (const float*)d_in[5];
    // d_in[6] = resolution = 16 => target_len == N => interp 32768->4096 + pos-add.

    char* ws = (char*)d_ws;
    bf16* qkv    = (bf16*)(ws);                  // 32768*1536 bf16 = 100,663,296 B
    bf16* ascr   = (bf16*)(ws + 100663296);      // 32768*512 bf16; written by kattn AFTER...
    bf16* posavg = (bf16*)(ws + 100663296);      // ...posavg (4 MB) is dead. Sequentially safe.
    bf16* wqT    = (bf16*)(ws + 134217728);      // 1536*512 bf16
    bf16* wpT    = (bf16*)(ws + 135790592);      // 512*512  bf16

    kprep<<<2048, 256, 0, stream>>>(w_qkv, w_proj, pos32, wqT, wpT, posavg);
    kgemmF<<<768, 512, 0, stream>>>(x, posavg, wqT, b_qkv, qkv);
    kattn<<<1024, 256, 0, stream>>>(qkv, ascr);
    kgemm8<float><<<256, 512, 0, stream>>>(ascr, wpT, b_proj, (float*)d_out, 32768, 512, 512);
}

// Round 14
// 141.140 us; speedup vs baseline: 1.4070x; 1.4070x over previous
//
#include <hip/hip_runtime.h>
#include <hip/hip_bf16.h>

using bf16 = __hip_bfloat16;
typedef __attribute__((ext_vector_type(8))) short short8;
typedef __attribute__((ext_vector_type(4))) float f32x4;

#define AS1U(p) ((const __attribute__((address_space(1))) unsigned int*)(p))
#define AS3U(p) ((__attribute__((address_space(3))) unsigned int*)(p))

__device__ __forceinline__ float bflo(unsigned u) { return __uint_as_float(u << 16); }
__device__ __forceinline__ float bfhi(unsigned u) { return __uint_as_float(u & 0xffff0000u); }
__device__ __forceinline__ unsigned short f2bf(float f) {
    union { float f; unsigned u; } v{f};
    unsigned r = v.u + 0x7fffu + ((v.u >> 16) & 1u);   // RNE (finite values only)
    return (unsigned short)(r >> 16);
}

// -------- fused prep: weight transposes (f32->bf16) + pos-interp-add (8-wide) --------
__global__ __launch_bounds__(256) void kprep(const float* __restrict__ wq,
                                             const float* __restrict__ wp,
                                             const float* __restrict__ x,
                                             const float* __restrict__ pos,
                                             bf16* __restrict__ wqT,
                                             bf16* __restrict__ wpT,
                                             bf16* __restrict__ xp) {
    int bid = blockIdx.x;
    __shared__ float t[32][33];
    if (bid < 1024) {
        const float* in; bf16* out; int Cc, bx, by;
        if (bid < 768) { in = wq; out = wqT; Cc = 1536; bx = bid % 48; by = bid / 48; }
        else { int i = bid - 768; in = wp; out = wpT; Cc = 512; bx = i & 15; by = i >> 4; }
        const int R = 512;
        int tx = threadIdx.x & 31, ty = threadIdx.x >> 5;
        int c0 = bx * 32, r0 = by * 32;
#pragma unroll
        for (int i = 0; i < 4; ++i)
            t[ty + i * 8][tx] = in[(size_t)(r0 + ty + i * 8) * Cc + c0 + tx];
        __syncthreads();
#pragma unroll
        for (int i = 0; i < 4; ++i)
            out[(size_t)(c0 + ty + i * 8) * R + r0 + tx] = __float2bfloat16(t[tx][ty + i * 8]);
    } else {
        size_t idx8 = (size_t)(bid - 1024) * 256 + threadIdx.x;  // 2,097,152 total
        size_t e = idx8 * 8;
        int c = (int)(e & 511);
        int n = (int)((e >> 9) & 4095);
        const float* xs = x + e;
        const float* p3 = pos + (size_t)(n * 8 + 3) * 512 + c;
        const float* p4 = pos + (size_t)(n * 8 + 4) * 512 + c;
        unsigned r[4];
#pragma unroll
        for (int h = 0; h < 2; ++h) {
            float4 xv = *(const float4*)(xs + h * 4);
            float4 a = *(const float4*)(p3 + h * 4);
            float4 b = *(const float4*)(p4 + h * 4);
            float v0 = xv.x + 0.5f * (a.x + b.x);
            float v1 = xv.y + 0.5f * (a.y + b.y);
            float v2 = xv.z + 0.5f * (a.z + b.z);
            float v3 = xv.w + 0.5f * (a.w + b.w);
            r[h * 2]     = (unsigned)f2bf(v0) | ((unsigned)f2bf(v1) << 16);
            r[h * 2 + 1] = (unsigned)f2bf(v2) | ((unsigned)f2bf(v3) << 16);
        }
        *(uint4*)(xp + e) = *(uint4*)r;
    }
}

// Shared LDS byte formula (verified R5-R13, 0 conflicts):
// byte(R,g) = (R>>4)*1024 + ((R>>1)&7)*128 + ((g | ((R&1)<<2)) ^ ((R>>1)&7))*16

// ======== 256x256 GEMM ring-4 (R7, best-proven 771 TF @ K=512): C = A @ Bt^T + bias ========
// 512 thr = 8 waves (2M x 4N); BK=32; 4-slot LDS ring (128 KiB); per region ONE
// compiler-scheduled {stage(t+3), 12 ds_read_b128, 32 MFMA}; lgkm(0) + counted vmcnt
// ladder (8/4/0) + sched_barrier(0) + one s_barrier. T2 swizzle both-sides, conflicts = 0.
template <typename OutT>
__global__ __launch_bounds__(512, 2) void kgemm8(const bf16* __restrict__ A,
                                                 const bf16* __restrict__ Bt,
                                                 const float* __restrict__ bias,
                                                 OutT* __restrict__ C,
                                                 int M, int N, int K_) {
    constexpr int K = 512;
    __shared__ __align__(16) char smem[131072];
    const int tid = threadIdx.x;
    const int lane = tid & 63, wave = tid >> 6;
    const int wm = wave >> 2, wn = wave & 3;
    const int fr = lane & 15;
    const int g = lane >> 4;

    const int p_rd = (((fr & 1) << 2) | g) ^ ((fr >> 1) & 7);
    const int tbA = (wm * 64 + (fr >> 1)) * 128 + p_rd * 16;
    const int tbB = (wn * 32 + (fr >> 1)) * 128 + p_rd * 16;

    const int ntn = N >> 8;
    const int nwg = gridDim.x;
    const int bid = blockIdx.x;
    const int swz = (bid & 7) * (nwg >> 3) + (bid >> 3);   // XCD swizzle (grid%8==0)
    const int bm = (swz / ntn) << 8;
    const int bn = (swz % ntn) << 8;

    const int q = (lane & 7) ^ (lane >> 3);
    const int srow = wave * 32 + 2 * (lane >> 3) + ((q >> 2) & 1);
    const int scol = (q & 3) * 8;
    const bf16* sA[2]; const bf16* sB[2];
#pragma unroll
    for (int g2 = 0; g2 < 2; ++g2) {
        sA[g2] = A  + (size_t)(bm + srow + g2 * 16) * K + scol;
        sB[g2] = Bt + (size_t)(bn + srow + g2 * 16) * K + scol;
    }
    const int dA0 = wave * 2048, dA1 = wave * 2048 + 1024;

    f32x4 acc[8][4];
#pragma unroll
    for (int i = 0; i < 8; ++i)
#pragma unroll
        for (int j = 0; j < 4; ++j) acc[i][j] = f32x4{0.f, 0.f, 0.f, 0.f};

    auto stageA = [&](int kt, int slot) {
        char* d = smem + slot * 32768;
        __builtin_amdgcn_global_load_lds(AS1U(sA[0] + kt * 32), AS3U(d + dA0), 16, 0, 0);
        __builtin_amdgcn_global_load_lds(AS1U(sA[1] + kt * 32), AS3U(d + dA1), 16, 0, 0);
    };
    auto stageB = [&](int kt, int slot) {
        char* d = smem + slot * 32768 + 16384;
        __builtin_amdgcn_global_load_lds(AS1U(sB[0] + kt * 32), AS3U(d + dA0), 16, 0, 0);
        __builtin_amdgcn_global_load_lds(AS1U(sB[1] + kt * 32), AS3U(d + dA1), 16, 0, 0);
    };

    stageA(0, 0); stageB(0, 0);
    stageA(1, 1); stageB(1, 1);
    stageA(2, 2); stageB(2, 2);
    asm volatile("s_waitcnt vmcnt(8)" ::: "memory");
    __builtin_amdgcn_s_barrier();

#pragma unroll
    for (int t = 0; t < 16; ++t) {
        const int rd = t & 3, wrs = (t + 3) & 3;
        const char* pa = smem + rd * 32768;
        const char* pb = pa + 16384;
        if (t < 13) { stageA(t + 3, wrs); stageB(t + 3, wrs); }
        short8 af[8], bfr[4];
#pragma unroll
        for (int mi = 0; mi < 8; ++mi) af[mi] = *(const short8*)(pa + tbA + mi * 1024);
#pragma unroll
        for (int nj = 0; nj < 4; ++nj) bfr[nj] = *(const short8*)(pb + tbB + nj * 1024);
#pragma unroll
        for (int mi = 0; mi < 8; ++mi)
#pragma unroll
            for (int nj = 0; nj < 4; ++nj)
                acc[mi][nj] = __builtin_amdgcn_mfma_f32_16x16x32_bf16(af[mi], bfr[nj], acc[mi][nj], 0, 0, 0);
        asm volatile("s_waitcnt lgkmcnt(0)" ::: "memory");
        if (t <= 12)      asm volatile("s_waitcnt vmcnt(8)" ::: "memory");
        else if (t == 13) asm volatile("s_waitcnt vmcnt(4)" ::: "memory");
        else if (t == 14) asm volatile("s_waitcnt vmcnt(0)" ::: "memory");
        __builtin_amdgcn_sched_barrier(0);
        __builtin_amdgcn_s_barrier();
    }

#pragma unroll
    for (int mi = 0; mi < 8; ++mi) {
#pragma unroll
        for (int nj = 0; nj < 4; ++nj) {
            int col = bn + wn * 64 + nj * 16 + fr;
            int row0 = bm + wm * 128 + mi * 16 + (lane >> 4) * 4;
            float bv = bias[col];
#pragma unroll
            for (int rr = 0; rr < 4; ++rr) {
                float val = acc[mi][nj][rr] + bv;
                if constexpr (sizeof(OutT) == 2)
                    C[(size_t)(row0 + rr) * N + col] = (OutT)__float2bfloat16(val);
                else
                    C[(size_t)(row0 + rr) * N + col] = (OutT)val;
            }
        }
    }
}

// ---------------- 8x8 per-token head attention + scrambled write ----------------
__global__ __launch_bounds__(256) void kattn(const bf16* __restrict__ qkv,
                                             bf16* __restrict__ oscr) {
    int T = blockIdx.x * 256 + threadIdx.x;
    int token = T >> 3, head = T & 7;
    int b = token >> 12, n = token & 4095;
    const bf16* row = qkv + (size_t)token * 1536;

    uint4 qp[8];
#pragma unroll
    for (int c = 0; c < 8; ++c) qp[c] = *(const uint4*)(row + head * 64 + c * 8);

    float s[8];
#pragma unroll
    for (int j = 0; j < 8; ++j) {
        float acc = 0.f;
#pragma unroll
        for (int c = 0; c < 8; ++c) {
            uint4 kp = *(const uint4*)(row + 512 + j * 64 + c * 8);
            const unsigned* ku = &kp.x; const unsigned* qu = &qp[c].x;
#pragma unroll
            for (int w = 0; w < 4; ++w) {
                acc = fmaf(bflo(qu[w]), bflo(ku[w]), acc);
                acc = fmaf(bfhi(qu[w]), bfhi(ku[w]), acc);
            }
        }
        s[j] = acc * 0.125f;
    }
    float mx = s[0];
#pragma unroll
    for (int j = 1; j < 8; ++j) mx = fmaxf(mx, s[j]);
    float sum = 0.f;
#pragma unroll
    for (int j = 0; j < 8; ++j) { s[j] = __expf(s[j] - mx); sum += s[j]; }
    float inv = 1.f / sum;
#pragma unroll
    for (int j = 0; j < 8; ++j) s[j] *= inv;

    float o[64];
#pragma unroll
    for (int d = 0; d < 64; ++d) o[d] = 0.f;
#pragma unroll
    for (int j = 0; j < 8; ++j) {
        float pj = s[j];
#pragma unroll
        for (int c = 0; c < 8; ++c) {
            uint4 vp = *(const uint4*)(row + 1024 + j * 64 + c * 8);
            const unsigned* vu = &vp.x;
#pragma unroll
            for (int w = 0; w < 4; ++w) {
                o[c * 8 + w * 2]     = fmaf(pj, bflo(vu[w]), o[c * 8 + w * 2]);
                o[c * 8 + w * 2 + 1] = fmaf(pj, bfhi(vu[w]), o[c * 8 + w * 2 + 1]);
            }
        }
    }
    size_t orow = (size_t)b * 4096 + head * 512 + (n >> 3);
    bf16* op = oscr + orow * 512 + (n & 7) * 64;
#pragma unroll
    for (int c = 0; c < 8; ++c) {
        unsigned rr[4];
#pragma unroll
        for (int w = 0; w < 4; ++w)
            rr[w] = (unsigned)f2bf(o[c * 8 + w * 2]) | ((unsigned)f2bf(o[c * 8 + w * 2 + 1]) << 16);
        *(uint4*)(op + c * 8) = *(uint4*)rr;
    }
}

extern "C" void kernel_launch(void* const* d_in, const int* in_sizes, int n_in,
                              void* d_out, int out_size, void* d_ws, size_t ws_size,
                              hipStream_t stream) {
    const float* x      = (const float*)d_in[0];
    const float* pos32  = (const float*)d_in[1];
    const float* w_qkv  = (const float*)d_in[2];
    const float* b_qkv  = (const float*)d_in[3];
    const float* w_proj = (const float*)d_in[4];
    const float* b_proj = (const float*)d_in[5];
    // d_in[6] = resolution = 16 => target_len == N => interp 32768->4096 + pos-add.

    char* ws = (char*)d_ws;
    bf16* xp   = (bf16*)(ws);                  //  32768*512  bf16
    bf16* qkv  = (bf16*)(ws + 33554432);       //  32768*1536 bf16
    bf16* wqT  = (bf16*)(ws + 134217728);      //  1536*512   bf16
    bf16* wpT  = (bf16*)(ws + 135790592);      //  512*512    bf16
    bf16* ascr = xp;  // alias: xp dead after qkv GEMM

    kprep<<<9216, 256, 0, stream>>>(w_qkv, w_proj, x, pos32, wqT, wpT, xp);
    kgemm8<bf16><<<768, 512, 0, stream>>>(xp, wqT, b_qkv, qkv, 32768, 1536, 512);
    kattn<<<1024, 256, 0, stream>>>(qkv, ascr);
    kgemm8<float><<<256, 512, 0, stream>>>(ascr, wpT, b_proj, (float*)d_out, 32768, 512, 512);
}